// Round 7
// baseline (32.368 us; speedup 1.0000x reference)
//
#include <hip/hip_runtime.h>

// Problem constants
constexpr int B_   = 2;
constexpr int CIN  = 64;
constexpr int N    = 128;
constexpr int T    = 24;
constexpr int HID  = 64;
constexpr int COUT = 64;
constexpr int NT   = N * T;             // 3072
constexpr int BT   = B_ * T;            // 48
constexpr int ATT_BLOCKS  = B_ * N;     // 256
constexpr int XT_BLOCKS   = 32;         // 2 b * 16 n-chunks of 8
constexpr int PREP_BLOCKS = ATT_BLOCKS + XT_BLOCKS + 1;  // 289

typedef __attribute__((ext_vector_type(8))) short short8;  // 8 bf16 MFMA frag
typedef __attribute__((ext_vector_type(4))) float f32x4;

__device__ inline unsigned short f2bf(float f) {   // RNE float->bf16
    unsigned u = __float_as_uint(f);
    return (unsigned short)((u + 0x7FFFu + ((u >> 16) & 1u)) >> 16);
}

// ---------------------------------------------------------------------------
// k_prep: three block-sections, ALL global reads/writes coalesced (>=128B runs,
// no sub-dword scattered stores anywhere — the R6 k_prep suspect).
//  [0,256):   att[b,0,i,j,t] -> attT bf16 [bt][i][j] (u32-packed) + asum f32.
//  [256,288): x[b,c',n,t]    -> xT  bf16 [bt][n][c'] (u32-packed).
//  288:       fused linear weights: WhT/WvT bf16 [c][c'] (k-major rows),
//             bh = b1@W2h, bvb2 = b1@W2v + b2   (MLP is linear: no activation)
// ---------------------------------------------------------------------------
__global__ __launch_bounds__(256) void k_prep(
    const float* __restrict__ x,
    const float* __restrict__ att,
    const float* __restrict__ W1,
    const float* __restrict__ b1,
    const float* __restrict__ W2,
    const float* __restrict__ b2,
    unsigned* __restrict__ xT32,      // [48][128][32] u32 (bf16 pairs over c')
    unsigned* __restrict__ attT32,    // [48][128][64] u32 (bf16 pairs over j)
    float* __restrict__ asum_g,       // [48][128]
    unsigned* __restrict__ WhT32,     // [64][32]
    unsigned* __restrict__ WvT32,     // [64][32]
    float* __restrict__ bh,
    float* __restrict__ bvb2)
{
    __shared__ __align__(16) unsigned smem_u32[6144];   // 24 KB, aliased
    float* tsf = (float*)smem_u32;

    const int tid = threadIdx.x;
    const int blk = blockIdx.x;

    if (blk < ATT_BLOCKS) {
        // ---- att transpose + row-sum (validated in R6) ----
        const int b = blk >> 7;
        const int i = blk & 127;
        const float* ab = att + ((size_t)b * N + i) * NT;   // flat [j*T+t]
#pragma unroll
        for (int u = 0; u < 12; ++u) {
            const int idx = tid + 256 * u;                  // j*24+t
            const int j = idx / T, t = idx - j * T;
            tsf[j * 25 + t] = ab[idx];                      // coalesced read
        }
        __syncthreads();
#pragma unroll
        for (int u = 0; u < 6; ++u) {
            const int e2 = tid + 256 * u;                   // t*64 + jp
            const int t = e2 >> 6, jp = e2 & 63, j = jp * 2;
            const unsigned pk = (unsigned)f2bf(tsf[j * 25 + t])
                              | ((unsigned)f2bf(tsf[(j + 1) * 25 + t]) << 16);
            attT32[((size_t)(b * T + t) * N + i) * 64 + jp] = pk;  // coalesced
        }
        // row sums (fp32 exact)
        float* psum = tsf + 3200;                           // [24][8]
        if (tid < 192) {
            const int t = tid >> 3, p = tid & 7;
            float s = 0.f;
#pragma unroll
            for (int q = 0; q < 16; ++q) s += tsf[(p * 16 + q) * 25 + t];
            psum[t * 8 + p] = s;
        }
        __syncthreads();
        if (tid < T) {
            float s = 0.f;
#pragma unroll
            for (int p = 0; p < 8; ++p) s += psum[tid * 8 + p];
            asum_g[(size_t)(b * T + tid) * N + i] = s;
        }
    } else if (blk < ATT_BLOCKS + XT_BLOCKS) {
        // ---- x transpose: x[b][c'][n0..n0+8][t] -> xT[bt][n][c'] bf16 ----
        const int tb = blk - ATT_BLOCKS;
        const int b  = tb >> 4;
        const int n0 = (tb & 15) * 8;
        // read: 64 c' rows x (8n*24t=192 f32) contiguous slabs, float4
#pragma unroll
        for (int u = 0; u < 12; ++u) {
            const int vidx = tid + 256 * u;                 // < 3072
            const int cp = vidx / 48, w48 = vidx - cp * 48;
            const float4 v = *(const float4*)(x + ((size_t)(b * CIN + cp) * NT)
                                              + n0 * T + w48 * 4);
            smem_u32[vidx * 2]     = (unsigned)f2bf(v.x) | ((unsigned)f2bf(v.y) << 16);
            smem_u32[vidx * 2 + 1] = (unsigned)f2bf(v.z) | ((unsigned)f2bf(v.w) << 16);
        }
        __syncthreads();
        // write: xT32[(bt)*128 + n][cp] — 128B coalesced runs
#pragma unroll
        for (int v = 0; v < 24; ++v) {
            const int oidx = tid + 256 * v;                 // < 6144
            const int t = oidx >> 8, rem = oidx & 255;
            const int n = rem >> 5, cp = rem & 31;
            const int r = n * T + t;                        // within-slab idx
            const unsigned w0 = smem_u32[cp * 192 + (r >> 1)];        // c'=2cp
            const unsigned w1 = smem_u32[cp * 192 + 96 + (r >> 1)];   // c'=2cp+1
            const unsigned v0 = (r & 1) ? (w0 >> 16) : (w0 & 0xFFFFu);
            const unsigned v1 = (r & 1) ? (w1 >> 16) : (w1 & 0xFFFFu);
            xT32[((size_t)(b * T + t) * N + n0 + n) * 32 + cp] = v0 | (v1 << 16);
        }
    } else {
        // ---- fused weights (1 block): Wh = W1@W2h, Wv = W1@W2v, biases ----
        const int c = tid & 63;
        const int g = tid >> 6;           // c' group of 16
        float aWh[16], aWv[16];
#pragma unroll
        for (int u = 0; u < 16; ++u) { aWh[u] = 0.f; aWv[u] = 0.f; }
        for (int q = 0; q < HID; ++q) {
            const float w2v = W2[q * COUT + c];
            const float w2h = W2[(HID + q) * COUT + c];
#pragma unroll
            for (int u = 0; u < 16; ++u) {
                const float w1v = W1[(g * 16 + u) * HID + q];  // wave-uniform
                aWh[u] += w1v * w2h;
                aWv[u] += w1v * w2v;
            }
        }
#pragma unroll
        for (int e = 0; e < 8; ++e) {
            WhT32[c * 32 + g * 8 + e] = (unsigned)f2bf(aWh[2 * e])
                                      | ((unsigned)f2bf(aWh[2 * e + 1]) << 16);
            WvT32[c * 32 + g * 8 + e] = (unsigned)f2bf(aWv[2 * e])
                                      | ((unsigned)f2bf(aWv[2 * e + 1]) << 16);
        }
        if (tid < 64) {
            float sv = 0.f, sh = 0.f;
            for (int q = 0; q < HID; ++q) {
                sv += b1[q] * W2[q * COUT + tid];
                sh += b1[q] * W2[(HID + q) * COUT + tid];
            }
            bh[tid]   = sh;
            bvb2[tid] = sv + b2[tid];
        }
    }
}

// ---------------------------------------------------------------------------
// k_all: whole pipeline per (bt, itile), pure MFMA. 384 blocks, 4 waves.
//  Phase 1: mh(128x64) = xT[bt] @ WhT^T (+bh) — wave w owns c-tile w:
//           8 n-tiles x 2 MFMA(K=32); D -> bf16 -> LDS mhT[64][136].
//           When ntile==itile also accumulate mv tile with WvT (A-frags reused).
//  Phase 2: einsum tile: acc(16i x 16c) = attT_tile(16x128) @ mhT (4 MFMA).
//  Epilogue: out[b][cc][i][t] = acc + asum_i * (accv + bvb2[cc]).
//  A/B frags share the k-mapping (q4*8+e) -> permutation cancels; C/D per m89.
// ---------------------------------------------------------------------------
__global__ __launch_bounds__(256) void k_all(
    const unsigned short* __restrict__ xTb,
    const unsigned short* __restrict__ attTb,
    const unsigned short* __restrict__ WhT,
    const unsigned short* __restrict__ WvT,
    const float* __restrict__ bh,
    const float* __restrict__ bvb2,
    const float* __restrict__ asum_g,
    float* __restrict__ out)
{
    __shared__ __align__(16) unsigned short mhT[64][136];   // 17.4 KB

    const int blk   = blockIdx.x;
    const int itile = blk & 7;
    const int bt    = blk >> 3;
    const int b     = bt / T;
    const int t     = bt - b * T;

    const int tid  = threadIdx.x;
    const int w    = tid >> 6;
    const int lane = tid & 63;
    const int c16  = lane & 15;
    const int q4   = lane >> 4;
    const int cc   = w * 16 + c16;       // this lane's output channel

    const unsigned short* whr = WhT + cc * 64;
    const short8 wh0 = *(const short8*)(whr + q4 * 8);
    const short8 wh1 = *(const short8*)(whr + 32 + q4 * 8);
    const unsigned short* wvr = WvT + cc * 64;
    const short8 wv0 = *(const short8*)(wvr + q4 * 8);
    const short8 wv1 = *(const short8*)(wvr + 32 + q4 * 8);
    const float bhc = bh[cc];
    const float bvc = bvb2[cc];

    const unsigned short* xpanel = xTb + (size_t)bt * N * CIN;

    f32x4 accv = {0.f, 0.f, 0.f, 0.f};
#pragma unroll
    for (int nt8 = 0; nt8 < 8; ++nt8) {
        const unsigned short* xr = xpanel + (nt8 * 16 + c16) * CIN;
        const short8 a0 = *(const short8*)(xr + q4 * 8);
        const short8 a1 = *(const short8*)(xr + 32 + q4 * 8);
        f32x4 d = {0.f, 0.f, 0.f, 0.f};
        d = __builtin_amdgcn_mfma_f32_16x16x32_bf16(a0, wh0, d, 0, 0, 0);
        d = __builtin_amdgcn_mfma_f32_16x16x32_bf16(a1, wh1, d, 0, 0, 0);
        // store mh tile (rows n = nt8*16 + q4*4 + e, col cc) as bf16, 8B write
        const unsigned lo = (unsigned)f2bf(d[0] + bhc) | ((unsigned)f2bf(d[1] + bhc) << 16);
        const unsigned hi = (unsigned)f2bf(d[2] + bhc) | ((unsigned)f2bf(d[3] + bhc) << 16);
        uint2 pk; pk.x = lo; pk.y = hi;
        *(uint2*)&mhT[cc][nt8 * 16 + q4 * 4] = pk;
        if (nt8 == itile) {   // block-uniform branch
            accv = __builtin_amdgcn_mfma_f32_16x16x32_bf16(a0, wv0, accv, 0, 0, 0);
            accv = __builtin_amdgcn_mfma_f32_16x16x32_bf16(a1, wv1, accv, 0, 0, 0);
        }
    }
    __syncthreads();

    // Phase 2: einsum
    f32x4 acc = {0.f, 0.f, 0.f, 0.f};
    const unsigned short* ar = attTb + ((size_t)bt * N + itile * 16 + c16) * N;
#pragma unroll
    for (int ks = 0; ks < 4; ++ks) {
        const short8 a  = *(const short8*)(ar + ks * 32 + q4 * 8);
        const short8 bb = *(const short8*)(&mhT[cc][ks * 32 + q4 * 8]);
        acc = __builtin_amdgcn_mfma_f32_16x16x32_bf16(a, bb, acc, 0, 0, 0);
    }

    // Epilogue
    const int il0 = itile * 16 + q4 * 4;
    const f32x4 as4 = *(const f32x4*)(asum_g + (size_t)bt * N + il0);
    float* ob = out + (((size_t)b * COUT + cc) * N + il0) * T + t;
#pragma unroll
    for (int e = 0; e < 4; ++e) {
        ob[e * T] = acc[e] + as4[e] * (accv[e] + bvc);
    }
}

// ---------------------------------------------------------------------------
extern "C" void kernel_launch(void* const* d_in, const int* in_sizes, int n_in,
                              void* d_out, int out_size, void* d_ws, size_t ws_size,
                              hipStream_t stream)
{
    const float* x   = (const float*)d_in[0];
    const float* att = (const float*)d_in[1];
    const float* W1  = (const float*)d_in[2];
    const float* b1  = (const float*)d_in[3];
    const float* W2  = (const float*)d_in[4];
    const float* b2  = (const float*)d_in[5];
    float* out = (float*)d_out;

    char* ws = (char*)d_ws;
    unsigned* xT32   = (unsigned*)(ws);                    //   786,432 B
    unsigned* attT32 = (unsigned*)(ws + 786432);           // 1,572,864 B
    float*    asum_g = (float*)   (ws + 2359296);          //    24,576 B
    unsigned* WhT32  = (unsigned*)(ws + 2383872);          //     8,192 B
    unsigned* WvT32  = (unsigned*)(ws + 2392064);          //     8,192 B
    float*    bh     = (float*)   (ws + 2400256);          //       256 B
    float*    bvb2   = (float*)   (ws + 2400512);          //       256 B

    k_prep<<<PREP_BLOCKS, 256, 0, stream>>>(x, att, W1, b1, W2, b2,
                                            xT32, attT32, asum_g,
                                            WhT32, WvT32, bh, bvb2);
    k_all<<<BT * 8, 256, 0, stream>>>((const unsigned short*)xT32,
                                      (const unsigned short*)attT32,
                                      (const unsigned short*)WhT32,
                                      (const unsigned short*)WvT32,
                                      bh, bvb2, asum_g, out);
}